// Round 4
// baseline (391.266 us; speedup 1.0000x reference)
//
#include <hip/hip_runtime.h>
#include <cstdint>
#include <cfloat>

// Problem constants (B=64, H=12, P=197, D=64)
#define NK 10
constexpr int Pp   = 197;
constexpr int Dd   = 64;
constexpr int ROWS = 64 * 12 * 197;      // 151296
constexpr int BLK  = 256;                // selection threads per block
constexpr int RPB  = 128;                // rows per selection block (2 lanes/row)
constexpr int NSLAB = ROWS / RPB;        // 1182 (exact)
constexpr int CH   = 32;                 // staging chunk width (cols)
constexpr int NCH  = Pp / CH;            // 6
constexpr int TAILC = Pp - NCH * CH;     // 5
constexpr int LDW  = CH + 4;             // 36-float row stride (16B aligned)
constexpr float INV_N = 1.0f / 9682944.0f;   // 1/(ROWS*D)

constexpr int RPB_B = 16;                // rows per gather block (16 waves)
constexpr int NB_B  = ROWS / RPB_B;      // 9456 (exact)

typedef float f4 __attribute__((ext_vector_type(4), aligned(4)));

__device__ __forceinline__ uint32_t fbits(float x) { return __float_as_uint(x); }
__device__ __forceinline__ float    bfl(uint32_t u) { return __uint_as_float(u); }

// Insert sorted pair (u<=v) into ascending a[0..9], keep top-10.
// c[s] = max3(a[s], min(a[s+1],v), min(a[s+2],u)); reads OLD a[s+1],a[s+2]
// (s ascending: writes trail reads). 29 VALU per 2 elements (v_max3_f32).
__device__ __forceinline__ void pair_insert(float a[NK], float x0, float x1) {
  float u = fminf(x0, x1), v = fmaxf(x0, x1);
#pragma unroll
  for (int s = 0; s < 8; ++s) {
    float t1 = fminf(a[s + 1], v), t2 = fminf(a[s + 2], u);
    a[s] = fmaxf(fmaxf(a[s], t1), t2);
  }
  float t1 = fminf(a[9], v);
  a[8] = fmaxf(fmaxf(a[8], t1), u);
  a[9] = fmaxf(a[9], v);
}

__device__ __forceinline__ void one_insert(float a[NK], float x) {
#pragma unroll
  for (int s = 0; s < 9; ++s) a[s] = fmaxf(a[s], fminf(x, a[s + 1]));
  a[9] = fmaxf(a[9], x);
}

// Load chunk c (32 cols x 128 rows) into 4 float4 regs, packing the column
// index into the low 8 mantissa bits (rel. perturbation 2^-16). Wave-instr
// coalescing: 8 full 128B lines per load.
__device__ __forceinline__ void load_chunk(const float* __restrict__ sp, int c,
                                           int t, f4 pf[4]) {
#pragma unroll
  for (int i = 0; i < 4; ++i) {
    int f = t + BLK * i;
    int rr = f >> 3, c4 = f & 7;
    const f4* p = (const f4*)(sp + rr * Pp + c * CH + c4 * 4);
    f4 q = __builtin_nontemporal_load(p);
    uint32_t cb = (uint32_t)(c * CH + c4 * 4);
    q.x = bfl((fbits(q.x) & 0xFFFFFF00u) | cb);
    q.y = bfl((fbits(q.y) & 0xFFFFFF00u) | (cb + 1));
    q.z = bfl((fbits(q.z) & 0xFFFFFF00u) | (cb + 2));
    q.w = bfl((fbits(q.w) & 0xFFFFFF00u) | (cb + 3));
    pf[i] = q;
  }
}

__device__ __forceinline__ void load_tail(const float* __restrict__ sp, int t,
                                          float tpf[3]) {
#pragma unroll
  for (int i = 0; i < 3; ++i) {
    int e = t + BLK * i;
    if (e < RPB * TAILC) {
      int rr = e / TAILC, j = e % TAILC;  // constant divisor -> magic mul
      float x = __builtin_nontemporal_load(sp + rr * Pp + NCH * CH + j);
      tpf[i] = bfl((fbits(x) & 0xFFFFFF00u) | (uint32_t)(NCH * CH + j));
    }
  }
}

// Kernel A: one block = 128-row slab of ONE tensor; lanes 2r/2r+1 scan the
// two halves of row r; bitonic-halver merge; emits packed softmaxed top-10.
__global__ __launch_bounds__(BLK, 8) void select_kernel(
    const float* __restrict__ att_s, const float* __restrict__ att_t,
    float* __restrict__ wpk /* [2][ROWS][NK] */) {
  __shared__ float tile[RPB][LDW];  // 18432 B -> 8 blocks/CU

  const int t = threadIdx.x;
  const int bi = blockIdx.x;
  const int tensor = (bi >= NSLAB) ? 1 : 0;
  const int slab = bi - tensor * NSLAB;
  const float* A = tensor ? att_t : att_s;
  const int row0 = slab * RPB;
  const float* sp = A + (size_t)row0 * Pp;
  const int r = t >> 1, h = t & 1;

  float a[NK];
#pragma unroll
  for (int k = 0; k < NK; ++k) a[k] = -FLT_MAX;

  f4 pf[4];
  float tpf[3];
  load_chunk(sp, 0, t, pf);

  for (int c = 0; c < NCH; ++c) {
    __syncthreads();  // previous tile fully consumed
#pragma unroll
    for (int i = 0; i < 4; ++i) {
      int f = t + BLK * i;
      *((f4*)&tile[f >> 3][(f & 7) * 4]) = pf[i];
    }
    __syncthreads();  // tile ready
    if (c + 1 < NCH) load_chunk(sp, c + 1, t, pf);
    else load_tail(sp, t, tpf);
    // consume my half: cols 16h..16h+15 of this chunk
#pragma unroll
    for (int j4 = 0; j4 < 4; ++j4) {
      f4 q = *((const f4*)&tile[r][16 * h + 4 * j4]);
      pair_insert(a, q.x, q.y);
      pair_insert(a, q.z, q.w);
    }
  }
  // tail: 5 cols (192..196); h0 takes {192,193,196}, h1 takes {194,195}
  __syncthreads();
#pragma unroll
  for (int i = 0; i < 3; ++i) {
    int e = t + BLK * i;
    if (e < RPB * TAILC) tile[e / TAILC][e % TAILC] = tpf[i];
  }
  __syncthreads();
  if (h == 0) {
    pair_insert(a, tile[r][0], tile[r][1]);
    one_insert(a, tile[r][4]);
  } else {
    pair_insert(a, tile[r][2], tile[r][3]);
  }

  // Bitonic halver merge of the two ascending half top-10 lists: the multiset
  // {max(a[i], b[9-i])} is exactly the top-10 of the union; each lane owns
  // i=0..4 of its own orientation -> 10 distinct outputs across the pair.
  float b5 = __shfl_xor(a[5], 1, 64), b6 = __shfl_xor(a[6], 1, 64);
  float b7 = __shfl_xor(a[7], 1, 64), b8 = __shfl_xor(a[8], 1, 64);
  float b9 = __shfl_xor(a[9], 1, 64);
  float m[5];
  m[0] = fmaxf(a[0], b9);
  m[1] = fmaxf(a[1], b8);
  m[2] = fmaxf(a[2], b7);
  m[3] = fmaxf(a[3], b6);
  m[4] = fmaxf(a[4], b5);
  float mx = fmaxf(a[9], b9);  // global max (exact, both lanes agree)

  float ev[5], s5 = 0.f;
#pragma unroll
  for (int i = 0; i < 5; ++i) { ev[i] = __expf(m[i] - mx); s5 += ev[i]; }
  float stot = s5 + __shfl_xor(s5, 1, 64);
  float inv = 1.0f / stot;

  // stage packed weights (idx byte survives min/max/shfl) then coalesced store
  float* flat = &tile[0][0];
  __syncthreads();  // all tile reads done
#pragma unroll
  for (int i = 0; i < 5; ++i) {
    float w = ev[i] * inv;  // >= ~1e-6 -> normal float, packing safe
    flat[r * NK + 5 * h + i] =
        bfl((fbits(w) & 0xFFFFFF00u) | (fbits(m[i]) & 0xFFu));
  }
  __syncthreads();
  float* dst = wpk + ((size_t)tensor * ROWS + row0) * NK;
#pragma unroll
  for (int i = 0; i < 5; ++i) dst[t + BLK * i] = flat[t + BLK * i];
}

// Kernel B: wave-per-row gather + squared-diff partial per block.
__global__ __launch_bounds__(1024) void gather_kernel(
    const float* __restrict__ v_s, const float* __restrict__ v_t,
    const float* __restrict__ wpk, float* __restrict__ partial) {
  const int t = threadIdx.x, wv = t >> 6, l = t & 63;
  int row = blockIdx.x * RPB_B + wv;
  row = __builtin_amdgcn_readfirstlane(row);  // force SGPR: scalar w loads
  const int bh = row / Pp;
  const float* vsb = v_s + (size_t)bh * (Pp * Dd) + l;
  const float* vtb = v_t + (size_t)bh * (Pp * Dd) + l;
  const float* w0 = wpk + (size_t)row * NK;
  const float* w1 = wpk + ((size_t)ROWS + row) * NK;

  float acc = 0.f;
#pragma unroll
  for (int k = 0; k < NK; ++k) {
    float w = w0[k];
    int idx = (int)(fbits(w) & 0xFFu);
    acc = fmaf(w, vsb[idx * Dd], acc);
  }
#pragma unroll
  for (int k = 0; k < NK; ++k) {
    float w = w1[k];
    int idx = (int)(fbits(w) & 0xFFu);
    acc = fmaf(-w, vtb[idx * Dd], acc);
  }
  float sq = acc * acc;
#pragma unroll
  for (int off = 32; off > 0; off >>= 1) sq += __shfl_xor(sq, off, 64);

  __shared__ float red[RPB_B];
  if (l == 0) red[wv] = sq;
  __syncthreads();
  if (t == 0) {
    float tot = 0.f;
#pragma unroll
    for (int i = 0; i < RPB_B; ++i) tot += red[i];
    partial[blockIdx.x] = tot;
  }
}

// Kernel C: single-block final reduction.
__global__ __launch_bounds__(1024) void reduce_kernel(
    const float* __restrict__ partial, float* __restrict__ out) {
  const int t = threadIdx.x, wv = t >> 6, l = t & 63;
  float s = 0.f;
  for (int i = t; i < NB_B; i += 1024) s += partial[i];
#pragma unroll
  for (int off = 32; off > 0; off >>= 1) s += __shfl_xor(s, off, 64);
  __shared__ float red[16];
  if (l == 0) red[wv] = s;
  __syncthreads();
  if (t == 0) {
    float tot = 0.f;
#pragma unroll
    for (int i = 0; i < 16; ++i) tot += red[i];
    out[0] = tot * INV_N;
  }
}

extern "C" void kernel_launch(void* const* d_in, const int* in_sizes, int n_in,
                              void* d_out, int out_size, void* d_ws,
                              size_t ws_size, hipStream_t stream) {
  const float* att_s = (const float*)d_in[0];
  const float* att_t = (const float*)d_in[1];
  const float* v_s = (const float*)d_in[2];
  const float* v_t = (const float*)d_in[3];
  float* out = (float*)d_out;

  float* wpk = (float*)d_ws;                     // 2*ROWS*NK floats = 12.1 MB
  float* partial = wpk + (size_t)2 * ROWS * NK;  // + NB_B floats

  select_kernel<<<2 * NSLAB, BLK, 0, stream>>>(att_s, att_t, wpk);
  gather_kernel<<<NB_B, 1024, 0, stream>>>(v_s, v_t, wpk, partial);
  reduce_kernel<<<1, 1024, 0, stream>>>(partial, out);
}

// Round 5
// 386.105 us; speedup vs baseline: 1.0134x; 1.0134x over previous
//
#include <hip/hip_runtime.h>
#include <cstdint>
#include <cfloat>

// Problem constants (B=64, H=12, P=197, D=64)
#define NK 10
constexpr int Pp   = 197;
constexpr int Dd   = 64;
constexpr int ROWS = 64 * 12 * 197;      // 151296
constexpr int BLK  = 256;                // selection threads per block
constexpr int RPB  = 128;                // rows per selection block (2 lanes/row)
constexpr int NSLAB = ROWS / RPB;        // 1182 (exact)
constexpr int CH   = 32;                 // staging chunk width (cols)
constexpr int NCH  = Pp / CH;            // 6
constexpr int TAILC = Pp - NCH * CH;     // 5
constexpr float INV_N = 1.0f / 9682944.0f;   // 1/(ROWS*D)

// gather config: 64 rows per block, XCD-swizzled
constexpr int GR_GRID = 2368;            // 8 * 296 (covers 2364 units + guard)
constexpr int GR_SLOT = GR_GRID / 8;     // 296 units per XCD

__device__ __forceinline__ uint32_t fbits(float x) { return __float_as_uint(x); }
__device__ __forceinline__ float    bfl(uint32_t u) { return __uint_as_float(u); }
__device__ __forceinline__ float    packi(float x, int idx) {
  return bfl((fbits(x) & 0xFFFFFF00u) | (uint32_t)idx);
}

// Async global->LDS DMA, 4B per lane. LDS dest = wave-uniform base + lane*4.
__device__ __forceinline__ void gll4(const float* g, float* l) {
  __builtin_amdgcn_global_load_lds(
      (const __attribute__((address_space(1))) void*)g,
      (__attribute__((address_space(3))) void*)l, 4, 0, 0);
}

// Insert sorted pair (u<=v) into ascending a[0..9], keep top-10.
// c[s] = max3(a[s], min(a[s+1],v), min(a[s+2],u)); reads OLD a[s+1],a[s+2]
// (s ascending: writes trail reads). ~14.5 VALU/element (v_max3_f32).
__device__ __forceinline__ void pair_insert(float a[NK], float x0, float x1) {
  float u = fminf(x0, x1), v = fmaxf(x0, x1);
#pragma unroll
  for (int s = 0; s < 8; ++s) {
    float t1 = fminf(a[s + 1], v), t2 = fminf(a[s + 2], u);
    a[s] = fmaxf(fmaxf(a[s], t1), t2);
  }
  float t1 = fminf(a[9], v);
  a[8] = fmaxf(fmaxf(a[8], t1), u);
  a[9] = fmaxf(a[9], v);
}

__device__ __forceinline__ void one_insert(float a[NK], float x) {
#pragma unroll
  for (int s = 0; s < 9; ++s) a[s] = fmaxf(a[s], fminf(x, a[s + 1]));
  a[9] = fmaxf(a[9], x);
}

// Kernel A: one block = 128-row slab of ONE tensor. global_load_lds staging
// into an unpadded 128x32 tile; lanes 2r/2r+1 consume parity halves of row r
// in a rotated order (bank = col; rotation -> exactly 2 lanes/bank = free).
__global__ __launch_bounds__(BLK, 8) void select_kernel(
    const float* __restrict__ att_s, const float* __restrict__ att_t,
    float* __restrict__ wpk /* [2][ROWS][NK] */) {
  __shared__ float tile[RPB * CH];       // 16384 B, row stride 32 (unpadded!)
  __shared__ float ttail[RPB * TAILC];   // 2560 B, row stride 5

  const int t = threadIdx.x;
  const int bi = blockIdx.x;
  const int tensor = (bi >= NSLAB) ? 1 : 0;
  const int slab = bi - tensor * NSLAB;
  const float* A = tensor ? att_t : att_s;
  const int row0 = slab * RPB;
  const float* sp = A + (size_t)row0 * Pp;

  const int r = t >> 1, h = t & 1;
  const int r2 = (t >> 2) & 15;   // rotation seed (2 rows share one seed)
  const int w64 = t & ~63;        // wave base within block (uniform per wave)

  float a[NK];
#pragma unroll
  for (int k = 0; k < NK; ++k) a[k] = -FLT_MAX;

  for (int c = 0; c < NCH; ++c) {
    if (c) __syncthreads();  // prior consume reads done before DMA overwrites
    // stage chunk c: 16 issues x (256 lanes x 4B) = 16 KB; global side is
    // 32 contiguous dwords per row -> fully coalesced.
#pragma unroll
    for (int i = 0; i < 16; ++i) {
      int f = i * BLK + t;
      int rr = f >> 5, col = f & 31;
      gll4(sp + rr * Pp + c * CH + col, &tile[i * BLK + w64]);
    }
    if (c == NCH - 1) {
      // stage tail (cols 192..196) alongside chunk 5; same vmcnt drain
#pragma unroll
      for (int i = 0; i < 3; ++i) {
        int f = i * BLK + t;
        if (f < RPB * TAILC) {  // wave-uniform cut (waves 2,3 skip at i=2)
          int rr = f / TAILC, col = f - rr * TAILC;
          gll4(sp + rr * Pp + NCH * CH + col, &ttail[i * BLK + w64]);
        }
      }
    }
    __syncthreads();  // compiler drains vmcnt(0) before s_barrier: tile ready

    // consume: 8 pairs of parity-h cols, rotated by r2 (2-way banks = free)
    const float* trow = &tile[r * CH];
    const int cb = c * CH + h;
#pragma unroll
    for (int j = 0; j < 8; ++j) {
      int qa = (r2 + j) & 15, qb = qa ^ 8;
      float xa = packi(trow[2 * qa + h], cb + 2 * qa);
      float xb = packi(trow[2 * qb + h], cb + 2 * qb);
      pair_insert(a, xa, xb);
    }
  }

  // tail consume: h0 -> cols {192,194,196}, h1 -> {193,195}
  {
    const float* trow = &ttail[r * TAILC];
    if (h == 0) {
      pair_insert(a, packi(trow[0], 192), packi(trow[2], 194));
      one_insert(a, packi(trow[4], 196));
    } else {
      pair_insert(a, packi(trow[1], 193), packi(trow[3], 195));
    }
  }

  // Bitonic halver merge of the two ascending half top-10 lists: multiset
  // {max(a[i], b[9-i])} is exactly the top-10 of the union; each lane owns 5.
  float b5 = __shfl_xor(a[5], 1, 64), b6 = __shfl_xor(a[6], 1, 64);
  float b7 = __shfl_xor(a[7], 1, 64), b8 = __shfl_xor(a[8], 1, 64);
  float b9 = __shfl_xor(a[9], 1, 64);
  float m[5];
  m[0] = fmaxf(a[0], b9);
  m[1] = fmaxf(a[1], b8);
  m[2] = fmaxf(a[2], b7);
  m[3] = fmaxf(a[3], b6);
  m[4] = fmaxf(a[4], b5);
  float mx = fmaxf(a[9], b9);  // global max (both lanes agree)

  float ev[5], s5 = 0.f;
#pragma unroll
  for (int i = 0; i < 5; ++i) { ev[i] = __expf(m[i] - mx); s5 += ev[i]; }
  float stot = s5 + __shfl_xor(s5, 1, 64);
  float inv = 1.0f / stot;

  // stage packed weights in (now free) tile, then coalesced store
  __syncthreads();  // all tile reads done before reuse
#pragma unroll
  for (int i = 0; i < 5; ++i) {
    float w = ev[i] * inv;  // >= ~1e-6 -> normal float, packing safe
    tile[r * NK + 5 * h + i] = packi(w, (int)(fbits(m[i]) & 0xFFu));
  }
  __syncthreads();
  float* dst = wpk + ((size_t)tensor * ROWS + row0) * NK;
#pragma unroll
  for (int i = 0; i < 5; ++i) dst[t + BLK * i] = tile[t + BLK * i];
}

// Kernel B: wave-per-row gather + squared-diff, XCD-swizzled so each XCD's
// L2 streams a contiguous 1/8 of the v tensors (slab fetched once per XCD).
__global__ __launch_bounds__(1024) void gather_kernel(
    const float* __restrict__ v_s, const float* __restrict__ v_t,
    const float* __restrict__ wpk, float* __restrict__ out) {
  const int t = threadIdx.x, wv = t >> 6, l = t & 63;
  const int u = (blockIdx.x & 7) * GR_SLOT + (blockIdx.x >> 3);  // 64-row unit

  float sq = 0.f;
  for (int it = 0; it < 4; ++it) {
    int row = u * 64 + wv * 4 + it;
    row = __builtin_amdgcn_readfirstlane(row);  // SGPR: scalar w loads
    if (row < ROWS) {
      const int bh = row / Pp;
      const float* vsb = v_s + (size_t)bh * (Pp * Dd) + l;
      const float* vtb = v_t + (size_t)bh * (Pp * Dd) + l;
      const float* w0 = wpk + (size_t)row * NK;
      const float* w1 = wpk + ((size_t)ROWS + row) * NK;
      float acc = 0.f;
#pragma unroll
      for (int k = 0; k < NK; ++k) {
        float w = w0[k];
        int idx = (int)(fbits(w) & 0xFFu);
        acc = fmaf(w, vsb[idx * Dd], acc);
      }
#pragma unroll
      for (int k = 0; k < NK; ++k) {
        float w = w1[k];
        int idx = (int)(fbits(w) & 0xFFu);
        acc = fmaf(-w, vtb[idx * Dd], acc);
      }
      sq = fmaf(acc, acc, sq);
    }
  }
#pragma unroll
  for (int off = 32; off > 0; off >>= 1) sq += __shfl_xor(sq, off, 64);

  __shared__ float red[16];
  if (l == 0) red[wv] = sq;
  __syncthreads();
  if (t == 0) {
    float tot = 0.f;
#pragma unroll
    for (int i = 0; i < 16; ++i) tot += red[i];
    atomicAdd(out, tot * INV_N);
  }
}

extern "C" void kernel_launch(void* const* d_in, const int* in_sizes, int n_in,
                              void* d_out, int out_size, void* d_ws,
                              size_t ws_size, hipStream_t stream) {
  const float* att_s = (const float*)d_in[0];
  const float* att_t = (const float*)d_in[1];
  const float* v_s = (const float*)d_in[2];
  const float* v_t = (const float*)d_in[3];
  float* out = (float*)d_out;

  float* wpk = (float*)d_ws;  // 2*ROWS*NK floats = 12.1 MB

  hipMemsetAsync(out, 0, sizeof(float), stream);  // graph-capturable node
  select_kernel<<<2 * NSLAB, BLK, 0, stream>>>(att_s, att_t, wpk);
  gather_kernel<<<GR_GRID, 1024, 0, stream>>>(v_s, v_t, wpk, out);
}